// Round 1
// baseline (90.572 us; speedup 1.0000x reference)
//
#include <hip/hip_runtime.h>

// ExemplarHead / ClassificationHead:
// logits[t,q,w,s] = -||Qc - proj_s||^2 / d, with proj = Rc (G+lam I)^-1 G (Gram trick, no SVD).
// T=32, n_way=5, n_shot=5, n_query=75, d=1024. Output fp32 (32,75,5,5).

constexpr int   T_   = 32;
constexpr int   NW   = 5;     // n_way
constexpr int   NS   = 5;     // n_shot
constexpr int   NQ   = 75;
constexpr int   D    = 1024;
constexpr int   D4   = D / 4;
constexpr float LAM  = 100000.0f;

__global__ __launch_bounds__(256) void exemplar_head_kernel(
    const float* __restrict__ query,    // (T, NQ, D)
    const float* __restrict__ support,  // (T, NW*NS, D)
    const float* __restrict__ noise,    // (NW, T, NS, D)
    float* __restrict__ out)            // (T, NQ, NW, NS)
{
    const int t    = blockIdx.x;
    const int w    = blockIdx.y;
    const int tid  = threadIdx.x;
    const int lane = tid & 63;
    const int wave = tid >> 6;

    __shared__ float Cs[NS][D];      // centered class reps (shot-major)
    __shared__ float meanS[D];
    __shared__ float gpart[4][15];   // per-wave Gram partials
    __shared__ float Ms[NS][NS];     // M = (G+lam I)^-1 G
    __shared__ float pdS[NS];        // diag(M^T G M)

    // ---- Phase 1: load support+noise, compute mean, center, stash in LDS ----
    // Each thread owns float4 slice i = 4*tid..4*tid+3 of every shot row.
    const float4* sup4 = (const float4*)(support + (size_t)(t * NW * NS + w * NS) * D);
    const float4* noi4 = (const float4*)(noise   + (size_t)((w * T_ + t) * NS) * D);
    float4 r[NS];
    float4 sum = make_float4(0.f, 0.f, 0.f, 0.f);
#pragma unroll
    for (int s = 0; s < NS; ++s) {
        float4 a = sup4[s * D4 + tid];
        float4 b = noi4[s * D4 + tid];
        float4 v = make_float4(a.x + b.x, a.y + b.y, a.z + b.z, a.w + b.w);
        r[s] = v;
        sum.x += v.x; sum.y += v.y; sum.z += v.z; sum.w += v.w;
    }
    float4 mn = make_float4(sum.x * 0.2f, sum.y * 0.2f, sum.z * 0.2f, sum.w * 0.2f);
    ((float4*)meanS)[tid] = mn;
#pragma unroll
    for (int s = 0; s < NS; ++s) {
        r[s].x -= mn.x; r[s].y -= mn.y; r[s].z -= mn.z; r[s].w -= mn.w;
        ((float4*)Cs[s])[tid] = r[s];
    }

    // ---- Phase 2: Gram matrix G = C^T C (15 unique entries), in-register ----
    float g[15];
    {
        int n = 0;
#pragma unroll
        for (int k = 0; k < NS; ++k)
#pragma unroll
            for (int l = k; l < NS; ++l) {
                g[n++] = r[k].x * r[l].x + r[k].y * r[l].y +
                         r[k].z * r[l].z + r[k].w * r[l].w;
            }
    }
#pragma unroll
    for (int off = 1; off < 64; off <<= 1)
#pragma unroll
        for (int n = 0; n < 15; ++n)
            g[n] += __shfl_xor(g[n], off, 64);
    if (lane == 0)
#pragma unroll
        for (int n = 0; n < 15; ++n) gpart[wave][n] = g[n];
    __syncthreads();

    // ---- Phase 2b: tiny 5x5 solve on thread 0 ----
    if (tid == 0) {
        float G[NS][NS];
        int n = 0;
        for (int k = 0; k < NS; ++k)
            for (int l = k; l < NS; ++l) {
                float v = gpart[0][n] + gpart[1][n] + gpart[2][n] + gpart[3][n];
                ++n;
                G[k][l] = v; G[l][k] = v;
            }
        // Gauss-Jordan: (G + lam I) M = G.  lam=1e5 dominates -> no pivoting needed.
        float A[NS][2 * NS];
        for (int i = 0; i < NS; ++i)
            for (int j = 0; j < NS; ++j) {
                A[i][j]      = G[i][j] + (i == j ? LAM : 0.0f);
                A[i][NS + j] = G[i][j];
            }
        for (int c = 0; c < NS; ++c) {
            float inv = 1.0f / A[c][c];
            for (int j = 0; j < 2 * NS; ++j) A[c][j] *= inv;
            for (int rI = 0; rI < NS; ++rI) {
                if (rI == c) continue;
                float f = A[rI][c];
                for (int j = 0; j < 2 * NS; ++j) A[rI][j] -= f * A[c][j];
            }
        }
        float M[NS][NS];
        for (int i = 0; i < NS; ++i)
            for (int j = 0; j < NS; ++j) {
                M[i][j] = A[i][NS + j];
                Ms[i][j] = M[i][j];
            }
        // pd[s] = M[:,s]^T G M[:,s]
        for (int s = 0; s < NS; ++s) {
            float acc = 0.f;
            for (int i = 0; i < NS; ++i) {
                float gi = 0.f;
                for (int j = 0; j < NS; ++j) gi += G[i][j] * M[j][s];
                acc += M[i][s] * gi;
            }
            pdS[s] = acc;
        }
    }
    __syncthreads();

    // ---- Phase 3: queries. Each wave strides over q; coalesced float4 loads ----
    const float4* q4base = (const float4*)(query + (size_t)t * NQ * D);
    for (int q = wave; q < NQ; q += 4) {
        float v[NS] = {0.f, 0.f, 0.f, 0.f, 0.f};
        float sq = 0.f;
        const float4* q4 = q4base + q * D4;
#pragma unroll
        for (int j = 0; j < 4; ++j) {
            int i4 = lane + 64 * j;
            float4 qq = q4[i4];
            float4 m  = ((const float4*)meanS)[i4];
            float4 qc = make_float4(qq.x - m.x, qq.y - m.y, qq.z - m.z, qq.w - m.w);
            sq += qc.x * qc.x + qc.y * qc.y + qc.z * qc.z + qc.w * qc.w;
#pragma unroll
            for (int k = 0; k < NS; ++k) {
                float4 c = ((const float4*)Cs[k])[i4];
                v[k] += qc.x * c.x + qc.y * c.y + qc.z * c.z + qc.w * c.w;
            }
        }
#pragma unroll
        for (int off = 1; off < 64; off <<= 1) {
            sq += __shfl_xor(sq, off, 64);
#pragma unroll
            for (int k = 0; k < NS; ++k) v[k] += __shfl_xor(v[k], off, 64);
        }
        if (lane < NS) {
            const int s = lane;
            float dot = 0.f;
#pragma unroll
            for (int k = 0; k < NS; ++k) dot += v[k] * Ms[k][s];
            float dist = sq - 2.0f * dot + pdS[s];
            out[(((size_t)t * NQ + q) * NW + w) * NS + s] = -dist * (1.0f / (float)D);
        }
    }
}

extern "C" void kernel_launch(void* const* d_in, const int* in_sizes, int n_in,
                              void* d_out, int out_size, void* d_ws, size_t ws_size,
                              hipStream_t stream) {
    const float* query   = (const float*)d_in[0];
    const float* support = (const float*)d_in[1];
    const float* noise   = (const float*)d_in[2];
    float* out = (float*)d_out;

    dim3 grid(T_, NW);
    dim3 block(256);
    exemplar_head_kernel<<<grid, block, 0, stream>>>(query, support, noise, out);
}

// Round 2
// 84.371 us; speedup vs baseline: 1.0735x; 1.0735x over previous
//
#include <hip/hip_runtime.h>

// ExemplarHead: logits[t,q,w,s] = -||Qc - proj_s||^2 / d
// Gram trick: proj = Rc M, M = (G+lam I)^-1 G, G = Rc^T Rc (5x5) -- no SVD.
// dist[q,s] = ||Qc_q||^2 - 2*(C^T Qc_q)·M[:,s] + (M^T G M)[s,s]
// Two kernels: A (160 blocks) preps C/mean/M/pd into ws; B (3040 blocks) does queries.

constexpr int   T_   = 32;
constexpr int   NW   = 5;
constexpr int   NS   = 5;
constexpr int   NQ   = 75;
constexpr int   D    = 1024;
constexpr int   D4   = D / 4;
constexpr float LAM  = 100000.0f;

// ws layout (floats)
constexpr size_t WS_C    = 0;                            // (160, NS, D)
constexpr size_t WS_MEAN = WS_C    + (size_t)T_ * NW * NS * D;  // (160, D)
constexpr size_t WS_M    = WS_MEAN + (size_t)T_ * NW * D;       // (160, 25)
constexpr size_t WS_PD   = WS_M    + (size_t)T_ * NW * 25;      // (160, 5)

__global__ __launch_bounds__(256) void prep_kernel(
    const float* __restrict__ support,  // (T, NW*NS, D)
    const float* __restrict__ noise,    // (NW, T, NS, D)
    float* __restrict__ ws)
{
    const int t    = blockIdx.x;
    const int w    = blockIdx.y;
    const int tw   = t * NW + w;
    const int tid  = threadIdx.x;
    const int lane = tid & 63;
    const int wave = tid >> 6;

    __shared__ float gpart[4][15];

    const float4* sup4 = (const float4*)(support + (size_t)(t * NW * NS + w * NS) * D);
    const float4* noi4 = (const float4*)(noise   + (size_t)((w * T_ + t) * NS) * D);
    float4 r[NS];
    float4 sum = make_float4(0.f, 0.f, 0.f, 0.f);
#pragma unroll
    for (int s = 0; s < NS; ++s) {
        float4 a = sup4[s * D4 + tid];
        float4 b = noi4[s * D4 + tid];
        float4 v = make_float4(a.x + b.x, a.y + b.y, a.z + b.z, a.w + b.w);
        r[s] = v;
        sum.x += v.x; sum.y += v.y; sum.z += v.z; sum.w += v.w;
    }
    float4 mn = make_float4(sum.x * 0.2f, sum.y * 0.2f, sum.z * 0.2f, sum.w * 0.2f);

    float4* c4 = (float4*)(ws + WS_C + (size_t)tw * NS * D);
    float4* m4 = (float4*)(ws + WS_MEAN + (size_t)tw * D);
    m4[tid] = mn;
#pragma unroll
    for (int s = 0; s < NS; ++s) {
        r[s].x -= mn.x; r[s].y -= mn.y; r[s].z -= mn.z; r[s].w -= mn.w;
        c4[s * D4 + tid] = r[s];
    }

    // Gram partials
    float g[15];
    {
        int n = 0;
#pragma unroll
        for (int k = 0; k < NS; ++k)
#pragma unroll
            for (int l = k; l < NS; ++l)
                g[n++] = r[k].x * r[l].x + r[k].y * r[l].y +
                         r[k].z * r[l].z + r[k].w * r[l].w;
    }
#pragma unroll
    for (int off = 1; off < 64; off <<= 1)
#pragma unroll
        for (int n = 0; n < 15; ++n)
            g[n] += __shfl_xor(g[n], off, 64);
    if (lane == 0)
#pragma unroll
        for (int n = 0; n < 15; ++n) gpart[wave][n] = g[n];
    __syncthreads();

    if (tid == 0) {
        float G[NS][NS];
        int n = 0;
        for (int k = 0; k < NS; ++k)
            for (int l = k; l < NS; ++l) {
                float v = gpart[0][n] + gpart[1][n] + gpart[2][n] + gpart[3][n];
                ++n;
                G[k][l] = v; G[l][k] = v;
            }
        float A[NS][2 * NS];
        for (int i = 0; i < NS; ++i)
            for (int j = 0; j < NS; ++j) {
                A[i][j]      = G[i][j] + (i == j ? LAM : 0.0f);
                A[i][NS + j] = G[i][j];
            }
        for (int c = 0; c < NS; ++c) {
            float inv = 1.0f / A[c][c];
            for (int j = 0; j < 2 * NS; ++j) A[c][j] *= inv;
            for (int rI = 0; rI < NS; ++rI) {
                if (rI == c) continue;
                float f = A[rI][c];
                for (int j = 0; j < 2 * NS; ++j) A[rI][j] -= f * A[c][j];
            }
        }
        float M[NS][NS];
        for (int i = 0; i < NS; ++i)
            for (int j = 0; j < NS; ++j) {
                M[i][j] = A[i][NS + j];
                ws[WS_M + (size_t)tw * 25 + i * NS + j] = M[i][j];
            }
        for (int s = 0; s < NS; ++s) {
            float acc = 0.f;
            for (int i = 0; i < NS; ++i) {
                float gi = 0.f;
                for (int j = 0; j < NS; ++j) gi += G[i][j] * M[j][s];
                acc += M[i][s] * gi;
            }
            ws[WS_PD + (size_t)tw * NS + s] = acc;
        }
    }
}

__global__ __launch_bounds__(256) void query_kernel(
    const float* __restrict__ query,    // (T, NQ, D)
    const float* __restrict__ ws,
    float* __restrict__ out)            // (T, NQ, NW, NS)
{
    const int t    = blockIdx.x;
    const int w    = blockIdx.y;
    const int qt   = blockIdx.z;
    const int tw   = t * NW + w;
    const int tid  = threadIdx.x;
    const int lane = tid & 63;
    const int wave = tid >> 6;

    __shared__ float CsF[NS * D];
    __shared__ float meanS[D];
    __shared__ float MsS[25];
    __shared__ float pdS[NS];

    // stage C (1536 float4) + mean (256 float4) + M/pd
    {
        const float4* csrc = (const float4*)(ws + WS_C + (size_t)tw * NS * D);
        float4* cdst = (float4*)CsF;
#pragma unroll
        for (int i = 0; i < 6; ++i)
            cdst[tid + 256 * i] = csrc[tid + 256 * i];
        ((float4*)meanS)[tid] = ((const float4*)(ws + WS_MEAN + (size_t)tw * D))[tid];
        if (tid < 25) MsS[tid] = ws[WS_M + (size_t)tw * 25 + tid];
        if (tid >= 32 && tid < 32 + NS) pdS[tid - 32] = ws[WS_PD + (size_t)tw * NS + (tid - 32)];
    }
    __syncthreads();

    const int q = qt * 4 + wave;
    if (q >= NQ) return;

    const float4* q4 = (const float4*)(query + ((size_t)t * NQ + q) * D);
    float v[NS] = {0.f, 0.f, 0.f, 0.f, 0.f};
    float sq = 0.f;
#pragma unroll
    for (int j = 0; j < 4; ++j) {
        int i4 = lane + 64 * j;
        float4 qq = q4[i4];
        float4 m  = ((const float4*)meanS)[i4];
        float4 qc = make_float4(qq.x - m.x, qq.y - m.y, qq.z - m.z, qq.w - m.w);
        sq += qc.x * qc.x + qc.y * qc.y + qc.z * qc.z + qc.w * qc.w;
#pragma unroll
        for (int k = 0; k < NS; ++k) {
            float4 c = ((const float4*)CsF)[k * D4 + i4];
            v[k] += qc.x * c.x + qc.y * c.y + qc.z * c.z + qc.w * c.w;
        }
    }
#pragma unroll
    for (int off = 1; off < 64; off <<= 1) {
        sq += __shfl_xor(sq, off, 64);
#pragma unroll
        for (int k = 0; k < NS; ++k) v[k] += __shfl_xor(v[k], off, 64);
    }
    if (lane < NS) {
        const int s = lane;
        float dot = 0.f;
#pragma unroll
        for (int k = 0; k < NS; ++k) dot += v[k] * MsS[k * NS + s];
        float dist = sq - 2.0f * dot + pdS[s];
        out[(((size_t)t * NQ + q) * NW + w) * NS + s] = -dist * (1.0f / (float)D);
    }
}

extern "C" void kernel_launch(void* const* d_in, const int* in_sizes, int n_in,
                              void* d_out, int out_size, void* d_ws, size_t ws_size,
                              hipStream_t stream) {
    const float* query   = (const float*)d_in[0];
    const float* support = (const float*)d_in[1];
    const float* noise   = (const float*)d_in[2];
    float* out = (float*)d_out;
    float* ws  = (float*)d_ws;

    dim3 gridA(T_, NW);
    prep_kernel<<<gridA, 256, 0, stream>>>(support, noise, ws);

    dim3 gridB(T_, NW, (NQ + 3) / 4);
    query_kernel<<<gridB, 256, 0, stream>>>(query, ws, out);
}